// Round 7
// baseline (255.245 us; speedup 1.0000x reference)
//
#include <hip/hip_runtime.h>
#include <math.h>

#define D_INN 256
#define D_HID 64
#define DTR 16
#define D_MEMM 128
#define BB 2
#define LL 2048
#define NROWS (BB*LL)   // 4096
#define NPROJ 736
#define NTOT 864        // 736 proj cols + 128 Q cols
#define SEG 16
#define SEGLEN (LL/SEG) // 128

typedef __attribute__((ext_vector_type(8))) short short8v;
typedef __attribute__((ext_vector_type(4))) float float4v;

static __device__ __forceinline__ unsigned short f2bf(float f) {
    unsigned int u = __float_as_uint(f);
    u += 0x7fff + ((u >> 16) & 1);   // RNE
    return (unsigned short)(u >> 16);
}

// ---------------- Kernel 1: proj = x @ [W_xproj | W_Q] (+b_Q), bf16 MFMA ----------------
__global__ __launch_bounds__(256) void k_gemm(const float* __restrict__ x,
        const float* __restrict__ Wx, const float* __restrict__ Wq,
        const float* __restrict__ bq, float* __restrict__ proj) {
    __shared__ unsigned short As[64][40];
    __shared__ unsigned short Bs[64][40];
    const int t = threadIdx.x;
    const int lane = t & 63, w = t >> 6;
    const int wr = w >> 1, wc = w & 1;
    const int row0 = blockIdx.y * 64, col0 = blockIdx.x * 64;

    float4v acc[2][2];
    #pragma unroll
    for (int i = 0; i < 2; i++)
        #pragma unroll
        for (int j = 0; j < 2; j++) acc[i][j] = (float4v)0.f;

    const int ar = t >> 2, akq = (t & 3) * 8;
    const int bk = t >> 3, bcq = (t & 7) * 8;

    for (int k0 = 0; k0 < D_INN; k0 += 32) {
        float4 a0 = *(const float4*)&x[(size_t)(row0 + ar) * D_INN + k0 + akq];
        float4 a1 = *(const float4*)&x[(size_t)(row0 + ar) * D_INN + k0 + akq + 4];
        float4 b0 = {}, b1 = {};
        int col = col0 + bcq;
        if (col + 8 <= NPROJ) {
            b0 = *(const float4*)&Wx[(size_t)(k0 + bk) * NPROJ + col];
            b1 = *(const float4*)&Wx[(size_t)(k0 + bk) * NPROJ + col + 4];
        } else if (col < NTOT) {
            b0 = *(const float4*)&Wq[(size_t)(k0 + bk) * D_MEMM + (col - NPROJ)];
            b1 = *(const float4*)&Wq[(size_t)(k0 + bk) * D_MEMM + (col - NPROJ) + 4];
        }
        __syncthreads();
        {
            unsigned short av[8] = { f2bf(a0.x), f2bf(a0.y), f2bf(a0.z), f2bf(a0.w),
                                     f2bf(a1.x), f2bf(a1.y), f2bf(a1.z), f2bf(a1.w) };
            *(short8v*)&As[ar][akq] = *(short8v*)av;
            Bs[bcq + 0][bk] = f2bf(b0.x); Bs[bcq + 1][bk] = f2bf(b0.y);
            Bs[bcq + 2][bk] = f2bf(b0.z); Bs[bcq + 3][bk] = f2bf(b0.w);
            Bs[bcq + 4][bk] = f2bf(b1.x); Bs[bcq + 5][bk] = f2bf(b1.y);
            Bs[bcq + 6][bk] = f2bf(b1.z); Bs[bcq + 7][bk] = f2bf(b1.w);
        }
        __syncthreads();
        short8v af[2], bf[2];
        const int fr = lane & 15, fk = (lane >> 4) * 8;
        af[0] = *(short8v*)&As[wr * 32 + fr][fk];
        af[1] = *(short8v*)&As[wr * 32 + 16 + fr][fk];
        bf[0] = *(short8v*)&Bs[wc * 32 + fr][fk];
        bf[1] = *(short8v*)&Bs[wc * 32 + 16 + fr][fk];
        #pragma unroll
        for (int i = 0; i < 2; i++)
            #pragma unroll
            for (int j = 0; j < 2; j++)
                acc[i][j] = __builtin_amdgcn_mfma_f32_16x16x32_bf16(af[i], bf[j], acc[i][j], 0, 0, 0);
    }
    #pragma unroll
    for (int i = 0; i < 2; i++)
        #pragma unroll
        for (int j = 0; j < 2; j++)
            #pragma unroll
            for (int e = 0; e < 4; e++) {
                int rr = row0 + wr * 32 + i * 16 + (lane >> 4) * 4 + e;
                int cc = col0 + wc * 32 + j * 16 + (lane & 15);
                if (cc < NTOT) {
                    float v = acc[i][j][e];
                    if (cc >= NPROJ) v += bq[cc - NPROJ];
                    proj[(size_t)rr * NTOT + cc] = v;
                }
            }
}

// ---------------- Kernel 2: delta / delta_l = softplus(dt @ W + b) ----------------
__global__ __launch_bounds__(256) void k_delta(const float* __restrict__ proj,
        const float* __restrict__ Wdt, const float* __restrict__ bdt,
        const float* __restrict__ Wdtl, const float* __restrict__ bdtl,
        float* __restrict__ delta, float* __restrict__ deltal) {
    __shared__ float sdt[16], sdtl[16];
    int row = blockIdx.x;
    int t = threadIdx.x;
    if (t < 16) sdt[t] = proj[(size_t)row * NTOT + 704 + t];
    else if (t < 32) sdtl[t - 16] = proj[(size_t)row * NTOT + 720 + (t - 16)];
    __syncthreads();
    float a1 = bdt[t], a2 = bdtl[t];
    #pragma unroll
    for (int r = 0; r < DTR; r++) {
        a1 += sdt[r] * Wdt[r * D_INN + t];
        a2 += sdtl[r] * Wdtl[r * D_INN + t];
    }
    delta[(size_t)row * D_INN + t]  = (a1 > 20.f) ? a1 : log1pf(expf(a1));
    deltal[(size_t)row * D_INN + t] = (a2 > 20.f) ? a2 : log1pf(expf(a2));
}

// ---------------- Kernel 3a: pass 1 — per-segment (sumδ, Q); scan1 also checkpoints ----
__global__ __launch_bounds__(256) void k_scan1(const float* __restrict__ x,
        const float* __restrict__ proj, const float* __restrict__ A,
        const float* __restrict__ delta, const float* __restrict__ deltal,
        float* __restrict__ Qbuf, float* __restrict__ SDbuf,
        float* __restrict__ cumd, float* __restrict__ mem) {
    __shared__ float Bsh[2][16][64];
    __shared__ float dus[2][16][8];
    const int t = threadIdx.x;
    const int w = t >> 6, n = t & 63;
    const int b = blockIdx.y;
    const int scan = blockIdx.z >> 4, seg = blockIdx.z & 15;
    const int d0 = blockIdx.x * 4, d = d0 + w;
    const size_t rowbase = (size_t)b * LL + (size_t)seg * SEGLEN;
    const float* dsel = (scan == 0 ? delta : deltal);
    const int cB = (scan == 0) ? 0 : 64;
    const float Aln = A[d * D_HID + n] * 1.44269504f;
    const int lli = t >> 4, lc4 = (t & 15) * 4;

    float4 nB = {}, du0 = {}, du1 = {};
    nB = *(const float4*)&proj[(rowbase + lli) * NTOT + cB + lc4];
    if (t < 16) {
        float4 dv4 = *(const float4*)&dsel[(rowbase + t) * D_INN + d0];
        float4 uv4 = *(const float4*)&x[(rowbase + t) * D_INN + d0];
        du0 = make_float4(dv4.x, dv4.x * uv4.x, dv4.y, dv4.y * uv4.y);
        du1 = make_float4(dv4.z, dv4.z * uv4.z, dv4.w, dv4.w * uv4.w);
    }
    *(float4*)&Bsh[0][lli][lc4] = nB;
    if (t < 16) { *(float4*)&dus[0][t][0] = du0; *(float4*)&dus[0][t][4] = du1; }
    __syncthreads();

    float s = 0.f, sd = 0.f;
    for (int c = 0; c < SEGLEN / 16; ++c) {
        const int cur = c & 1;
        const bool hn = (c + 1 < SEGLEN / 16);
        if (hn) {
            size_t row = rowbase + (c + 1) * 16;
            nB = *(const float4*)&proj[(row + lli) * NTOT + cB + lc4];
            if (t < 16) {
                float4 dv4 = *(const float4*)&dsel[(row + t) * D_INN + d0];
                float4 uv4 = *(const float4*)&x[(row + t) * D_INN + d0];
                du0 = make_float4(dv4.x, dv4.x * uv4.x, dv4.y, dv4.y * uv4.y);
                du1 = make_float4(dv4.z, dv4.z * uv4.z, dv4.w, dv4.w * uv4.w);
            }
        }
        #pragma unroll
        for (int li = 0; li < 16; ++li) {
            float2 dp = *(const float2*)&dus[cur][li][2 * w];
            float Bv = Bsh[cur][li][n];
            float dA = exp2f(dp.x * Aln);
            s = fmaf(dA, s, dp.y * Bv);
            sd += dp.x;
            if (scan == 1 && li == 0) {
                float v = s;
                #pragma unroll
                for (int off = 32; off >= 1; off >>= 1) v += __shfl_xor(v, off);
                if (n == 0) {
                    int k = seg * 8 + c;
                    mem[((size_t)b * 128 + k) * D_INN + d] = v;
                    cumd[(((size_t)b * SEG + seg) * 8 + c) * D_INN + d] = sd;
                }
            }
        }
        if (hn) {
            const int nxt = cur ^ 1;
            *(float4*)&Bsh[nxt][lli][lc4] = nB;
            if (t < 16) { *(float4*)&dus[nxt][t][0] = du0; *(float4*)&dus[nxt][t][4] = du1; }
        }
        __syncthreads();
    }
    Qbuf[((((size_t)scan * 2 + b) * SEG + seg) * D_INN + d) * 64 + n] = s;
    if (n == 0) SDbuf[(((size_t)scan * 2 + b) * SEG + seg) * D_INN + d] = sd;
}

// ---------------- Kernel 3b: pass 2 — scan 0 only, emit y ----------------
__global__ __launch_bounds__(256) void k_scan2(const float* __restrict__ x,
        const float* __restrict__ proj, const float* __restrict__ A,
        const float* __restrict__ Dp, const float* __restrict__ delta,
        const float* __restrict__ Qbuf, const float* __restrict__ SDbuf,
        float* __restrict__ y) {
    __shared__ float Bsh[2][8][64];
    __shared__ float Csh[2][8][64];
    __shared__ float dus[2][8][8];
    __shared__ float xs[2][8][4];
    __shared__ float rbuf[4][8][65];
    const int t = threadIdx.x;
    const int w = t >> 6, n = t & 63;
    const int b = blockIdx.y, seg = blockIdx.z;
    const int d0 = blockIdx.x * 4, d = d0 + w;
    const size_t rowbase = (size_t)b * LL + (size_t)seg * SEGLEN;
    const float Aln = A[d * D_HID + n] * 1.44269504f;
    const float Dpv = Dp[d];
    const int lli = (t & 127) >> 4, lc4 = (t & 15) * 4;
    const bool isB = (t < 128);
    const int rli = n >> 3, g = n & 7;

    float s = 0.f;
    for (int k = 0; k < seg; ++k) {
        float sdk = SDbuf[(((size_t)b * SEG + k) * D_INN + d)];
        float Qk = Qbuf[(((size_t)b * SEG + k) * D_INN + d) * 64 + n];
        s = fmaf(exp2f(sdk * Aln), s, Qk);
    }

    float4 nT = {}, du0 = {}, du1 = {}, nU = {};
    {
        size_t row = rowbase + lli;
        if (isB) nT = *(const float4*)&proj[row * NTOT + lc4];
        else nT = *(const float4*)&proj[row * NTOT + 128 + lc4];
        if (t < 8) {
            float4 dv4 = *(const float4*)&delta[(rowbase + t) * D_INN + d0];
            nU = *(const float4*)&x[(rowbase + t) * D_INN + d0];
            du0 = make_float4(dv4.x, dv4.x * nU.x, dv4.y, dv4.y * nU.y);
            du1 = make_float4(dv4.z, dv4.z * nU.z, dv4.w, dv4.w * nU.w);
        }
    }
    if (isB) *(float4*)&Bsh[0][lli][lc4] = nT;
    else *(float4*)&Csh[0][lli][lc4] = nT;
    if (t < 8) {
        *(float4*)&dus[0][t][0] = du0; *(float4*)&dus[0][t][4] = du1;
        *(float4*)&xs[0][t][0] = nU;
    }
    __syncthreads();

    for (int c = 0; c < SEGLEN / 8; ++c) {
        const int cur = c & 1;
        const bool hn = (c + 1 < SEGLEN / 8);
        if (hn) {
            size_t row = rowbase + (c + 1) * 8 + lli;
            if (isB) nT = *(const float4*)&proj[row * NTOT + lc4];
            else nT = *(const float4*)&proj[row * NTOT + 128 + lc4];
            if (t < 8) {
                size_t r2 = rowbase + (c + 1) * 8 + t;
                float4 dv4 = *(const float4*)&delta[r2 * D_INN + d0];
                nU = *(const float4*)&x[r2 * D_INN + d0];
                du0 = make_float4(dv4.x, dv4.x * nU.x, dv4.y, dv4.y * nU.y);
                du1 = make_float4(dv4.z, dv4.z * nU.z, dv4.w, dv4.w * nU.w);
            }
        }
        #pragma unroll
        for (int li = 0; li < 8; ++li) {
            float2 dp = *(const float2*)&dus[cur][li][2 * w];
            float Bv = Bsh[cur][li][n];
            float dA = exp2f(dp.x * Aln);
            s = fmaf(dA, s, dp.y * Bv);
            rbuf[w][li][n] = s * Csh[cur][li][n];
        }
        {
            float acc = 0.f;
            #pragma unroll
            for (int j = 0; j < 8; ++j) acc += rbuf[w][rli][g * 8 + j];
            acc += __shfl_xor(acc, 1);
            acc += __shfl_xor(acc, 2);
            acc += __shfl_xor(acc, 4);
            if (g == 0) {
                float xv = xs[cur][rli][w];
                size_t row = rowbase + c * 8 + rli;
                y[row * D_INN + d] = acc + xv * Dpv;
            }
        }
        if (hn) {
            const int nxt = cur ^ 1;
            if (isB) *(float4*)&Bsh[nxt][lli][lc4] = nT;
            else *(float4*)&Csh[nxt][lli][lc4] = nT;
            if (t < 8) {
                *(float4*)&dus[nxt][t][0] = du0; *(float4*)&dus[nxt][t][4] = du1;
                *(float4*)&xs[nxt][t][0] = nU;
            }
        }
        __syncthreads();
    }
}

// ---------------- Kernel 3c-1: segment-boundary states for scan=1 ----------------
__global__ __launch_bounds__(256) void k_sin(const float* __restrict__ A,
        const float* __restrict__ Qbuf, const float* __restrict__ SDbuf,
        float* __restrict__ Sin) {
    const int t = threadIdx.x, w = t >> 6, n = t & 63;
    const int b = blockIdx.y;
    const int d = blockIdx.x * 4 + w;
    const float Aln = A[d * D_HID + n] * 1.44269504f;
    float s = 0.f;
    #pragma unroll
    for (int seg = 0; seg < SEG; ++seg) {
        if (seg > 0) Sin[(((size_t)b * SEG + seg) * D_INN + d) * 64 + n] = s;
        float sdk = SDbuf[((size_t)(2 + b) * SEG + seg) * D_INN + d];
        float Qk = Qbuf[(((size_t)(2 + b) * SEG + seg) * D_INN + d) * 64 + n];
        s = fmaf(exp2f(sdk * Aln), s, Qk);
    }
}

// ---------------- Kernel 3c-2: parallel mem correction ----------------
__global__ __launch_bounds__(256) void k_fix(const float* __restrict__ A,
        const float* __restrict__ Sin, const float* __restrict__ cumd,
        float* __restrict__ mem) {
    const int t = threadIdx.x, w = t >> 6, n = t & 63;
    const int k = 8 + blockIdx.y;
    const int b = blockIdx.z;
    const int d = blockIdx.x * 4 + w;
    const int seg = k >> 3;
    const float Aln = A[d * D_HID + n] * 1.44269504f;
    float cum = cumd[((size_t)b * 128 + k) * D_INN + d];
    float sv = Sin[(((size_t)b * SEG + seg) * D_INN + d) * 64 + n];
    float v = exp2f(cum * Aln) * sv;
    #pragma unroll
    for (int off = 32; off >= 1; off >>= 1) v += __shfl_xor(v, off);
    if (n == 0) mem[((size_t)b * 128 + k) * D_INN + d] += v;
}

// ---------------- Kernel 4: K, V = memory @ W_K/V + b ----------------
__global__ __launch_bounds__(128) void k_kv(const float* __restrict__ mem,
        const float* __restrict__ Wk, const float* __restrict__ bk,
        const float* __restrict__ Wv, const float* __restrict__ bv,
        float* __restrict__ K, float* __restrict__ V) {
    __shared__ float mrow[256];
    int k = blockIdx.x, b = blockIdx.y;
    int t = threadIdx.x;
    const float* mr = mem + ((size_t)b * 128 + k) * D_INN;
    mrow[t] = mr[t];
    mrow[t + 128] = mr[t + 128];
    __syncthreads();
    float aK = bk[t], aV = bv[t];
    for (int dd = 0; dd < D_INN; dd++) {
        float m = mrow[dd];
        aK += m * Wk[dd * D_MEMM + t];
        aV += m * Wv[dd * D_MEMM + t];
    }
    K[((size_t)b * 128 + k) * D_MEMM + t] = aK;
    V[((size_t)b * 128 + k) * D_MEMM + t] = aV;
}

// ---------------- Kernel 4b: VWo[b] = V[b] (128x128) @ Wo (128x256) ----------------
// grid (8, 2); block 256 = 4 waves; wave -> 4 rows, lane -> 4 cols.
__global__ __launch_bounds__(256) void k_vwo(const float* __restrict__ V,
        const float* __restrict__ Wo, float* __restrict__ VWo) {
    __shared__ float vs[16][132];
    const int t = threadIdx.x, b = blockIdx.y;
    const int r0 = blockIdx.x * 16;
    {
        int r = t >> 4, c8 = (t & 15) * 8;
        const float* src = &V[((size_t)b * 128 + r0 + r) * D_MEMM + c8];
        *(float4*)&vs[r][c8] = *(const float4*)src;
        *(float4*)&vs[r][c8 + 4] = *(const float4*)(src + 4);
    }
    __syncthreads();
    const int w = t >> 6, lane = t & 63;
    const int c0 = lane * 4;
    float acc[4][4] = {};
    #pragma unroll 8
    for (int k = 0; k < 128; k += 4) {
        float4 wv[4];
        #pragma unroll
        for (int r = 0; r < 4; ++r) wv[r] = *(float4*)&vs[w * 4 + r][k];
        #pragma unroll
        for (int kk = 0; kk < 4; ++kk) {
            float4 wo = *(const float4*)&Wo[(size_t)(k + kk) * D_INN + c0];
            #pragma unroll
            for (int r = 0; r < 4; ++r) {
                float vk = (kk == 0 ? wv[r].x : kk == 1 ? wv[r].y : kk == 2 ? wv[r].z : wv[r].w);
                acc[r][0] += vk * wo.x; acc[r][1] += vk * wo.y;
                acc[r][2] += vk * wo.z; acc[r][3] += vk * wo.w;
            }
        }
    }
    #pragma unroll
    for (int r = 0; r < 4; ++r)
        *(float4*)&VWo[((size_t)b * 128 + r0 + w * 4 + r) * D_INN + c0] =
            make_float4(acc[r][0], acc[r][1], acc[r][2], acc[r][3]);
}

// ---------------- Kernel 5: attention + epilogue, 16 rows per block ----------------
// grid (128, 2); block 256. Phases: QK^T -> softmax -> w@VWo -> epilogue.
__global__ __launch_bounds__(256) void k_attn(const float* __restrict__ x,
        const float* __restrict__ proj, const float* __restrict__ y,
        const float* __restrict__ K, const float* __restrict__ VWo,
        const float* __restrict__ bo, float* __restrict__ out) {
    __shared__ float qs[16][132];
    __shared__ float ws[16][132];
    __shared__ float denom[16];
    const int t = threadIdx.x;
    const int b = blockIdx.y;
    const int r0 = blockIdx.x * 16;
    const size_t rowbase = (size_t)b * LL + r0;
    {   // stage q: 16 rows x 128
        int r = t >> 4, c8 = (t & 15) * 8;
        const float* src = &proj[(rowbase + r) * NTOT + NPROJ + c8];
        *(float4*)&qs[r][c8] = *(const float4*)src;
        *(float4*)&qs[r][c8 + 4] = *(const float4*)(src + 4);
    }
    __syncthreads();
    {   // QK^T: thread -> key k, 8 rows
        const int k = t & 127, rg = (t >> 7) * 8;
        const float* Kr = K + ((size_t)b * 128 + k) * D_MEMM;
        float acc[8] = {};
        #pragma unroll 8
        for (int m = 0; m < 128; m += 4) {
            float4 kv = *(const float4*)&Kr[m];
            #pragma unroll
            for (int r = 0; r < 8; ++r) {
                float4 qv = *(const float4*)&qs[rg + r][m];
                acc[r] += qv.x * kv.x + qv.y * kv.y + qv.z * kv.z + qv.w * kv.w;
            }
        }
        #pragma unroll
        for (int r = 0; r < 8; ++r) ws[rg + r][k] = acc[r] * 0.125f;
    }
    __syncthreads();
    {   // softmax: row r = t>>4, lane-sub j = t&15 handles 8 values
        const int r = t >> 4, j = t & 15;
        float4 v0 = *(float4*)&ws[r][j * 8];
        float4 v1 = *(float4*)&ws[r][j * 8 + 4];
        float mx = fmaxf(fmaxf(fmaxf(v0.x, v0.y), fmaxf(v0.z, v0.w)),
                         fmaxf(fmaxf(v1.x, v1.y), fmaxf(v1.z, v1.w)));
        #pragma unroll
        for (int o = 1; o < 16; o <<= 1) mx = fmaxf(mx, __shfl_xor(mx, o));
        v0.x = expf(v0.x - mx); v0.y = expf(v0.y - mx);
        v0.z = expf(v0.z - mx); v0.w = expf(v0.w - mx);
        v1.x = expf(v1.x - mx); v1.y = expf(v1.y - mx);
        v1.z = expf(v1.z - mx); v1.w = expf(v1.w - mx);
        float sum = v0.x + v0.y + v0.z + v0.w + v1.x + v1.y + v1.z + v1.w;
        #pragma unroll
        for (int o = 1; o < 16; o <<= 1) sum += __shfl_xor(sum, o);
        *(float4*)&ws[r][j * 8] = v0;
        *(float4*)&ws[r][j * 8 + 4] = v1;
        if (j == 0) denom[r] = sum;
    }
    __syncthreads();
    {   // w @ VWo: wave -> 4 rows, lane -> 4 cols; fused epilogue
        const int w = t >> 6, lane = t & 63;
        const int c0 = lane * 4;
        const float* vb = VWo + (size_t)b * 128 * D_INN + c0;
        float acc[4][4] = {};
        #pragma unroll 8
        for (int k = 0; k < 128; k += 4) {
            float4 wv[4];
            #pragma unroll
            for (int r = 0; r < 4; ++r) wv[r] = *(float4*)&ws[w * 4 + r][k];
            #pragma unroll
            for (int kk = 0; kk < 4; ++kk) {
                float4 vw = *(const float4*)&vb[(size_t)(k + kk) * D_INN];
                #pragma unroll
                for (int r = 0; r < 4; ++r) {
                    float wk = (kk == 0 ? wv[r].x : kk == 1 ? wv[r].y : kk == 2 ? wv[r].z : wv[r].w);
                    acc[r][0] += wk * vw.x; acc[r][1] += wk * vw.y;
                    acc[r][2] += wk * vw.z; acc[r][3] += wk * vw.w;
                }
            }
        }
        float4 bov = *(const float4*)&bo[c0];
        #pragma unroll
        for (int r = 0; r < 4; ++r) {
            size_t rr = rowbase + w * 4 + r;
            float dn = 1.f / denom[w * 4 + r];
            float4 yv = *(const float4*)&y[rr * D_INN + c0];
            float4 xv = *(const float4*)&x[rr * D_INN + c0];
            float4 Ev = *(const float4*)&proj[rr * NTOT + 192 + c0];
            float4 Fv = *(const float4*)&proj[rr * NTOT + 448 + c0];
            float4 o;
            o.x = yv.x + (acc[r][0] * dn + bov.x) * Ev.x + xv.x * Fv.x;
            o.y = yv.y + (acc[r][1] * dn + bov.y) * Ev.y + xv.y * Fv.y;
            o.z = yv.z + (acc[r][2] * dn + bov.z) * Ev.z + xv.z * Fv.z;
            o.w = yv.w + (acc[r][3] * dn + bov.w) * Ev.w + xv.w * Fv.w;
            *(float4*)&out[rr * D_INN + c0] = o;
        }
    }
}

extern "C" void kernel_launch(void* const* d_in, const int* in_sizes, int n_in,
                              void* d_out, int out_size, void* d_ws, size_t ws_size,
                              hipStream_t stream) {
    const float* x    = (const float*)d_in[0];
    const float* Wx   = (const float*)d_in[1];
    const float* Wdt  = (const float*)d_in[2];
    const float* bdt  = (const float*)d_in[3];
    const float* Wdtl = (const float*)d_in[4];
    const float* bdtl = (const float*)d_in[5];
    const float* A    = (const float*)d_in[6];
    const float* Dp   = (const float*)d_in[7];
    const float* Wq   = (const float*)d_in[8];
    const float* bq   = (const float*)d_in[9];
    const float* Wk   = (const float*)d_in[10];
    const float* bk   = (const float*)d_in[11];
    const float* Wv   = (const float*)d_in[12];
    const float* bv   = (const float*)d_in[13];
    const float* Wo   = (const float*)d_in[14];
    const float* bo   = (const float*)d_in[15];
    float* out = (float*)d_out;
    float* ws = (float*)d_ws;

    float* proj   = ws;                                    // 4096*864
    float* delta  = proj + (size_t)NROWS * NTOT;           // 4096*256
    float* deltal = delta + (size_t)NROWS * D_INN;         // 4096*256
    float* yb     = deltal + (size_t)NROWS * D_INN;        // 4096*256
    float* mem    = yb + (size_t)NROWS * D_INN;            // 2*128*256
    float* Kb     = mem + (size_t)BB * 128 * D_INN;        // 2*128*128
    float* Vb     = Kb + (size_t)BB * 128 * D_MEMM;        // 2*128*128
    float* Qbuf   = Vb + (size_t)BB * 128 * D_MEMM;        // 4*16*256*64
    float* SDbuf  = Qbuf + (size_t)4 * SEG * D_INN * 64;   // 4*16*256
    float* cumd   = SDbuf + (size_t)4 * SEG * D_INN;       // 2*16*8*256
    float* Sin    = cumd + (size_t)BB * SEG * 8 * D_INN;   // 2*16*256*64
    float* VWo    = Sin + (size_t)BB * SEG * D_INN * 64;   // 2*128*256

    hipLaunchKernelGGL(k_gemm, dim3(14, 64), dim3(256), 0, stream, x, Wx, Wq, bq, proj);
    hipLaunchKernelGGL(k_delta, dim3(NROWS), dim3(256), 0, stream,
                       proj, Wdt, bdt, Wdtl, bdtl, delta, deltal);
    hipLaunchKernelGGL(k_scan1, dim3(64, 2, 32), dim3(256), 0, stream,
                       x, proj, A, delta, deltal, Qbuf, SDbuf, cumd, mem);
    hipLaunchKernelGGL(k_scan2, dim3(64, 2, 16), dim3(256), 0, stream,
                       x, proj, A, Dp, delta, Qbuf, SDbuf, yb);
    hipLaunchKernelGGL(k_sin, dim3(64, 2), dim3(256), 0, stream,
                       A, Qbuf, SDbuf, Sin);
    hipLaunchKernelGGL(k_fix, dim3(64, 120, 2), dim3(256), 0, stream,
                       A, Sin, cumd, mem);
    hipLaunchKernelGGL(k_kv, dim3(128, 2), dim3(128), 0, stream,
                       mem, Wk, bk, Wv, bv, Kb, Vb);
    hipLaunchKernelGGL(k_vwo, dim3(8, 2), dim3(256), 0, stream, Vb, Wo, VWo);
    hipLaunchKernelGGL(k_attn, dim3(128, 2), dim3(256), 0, stream,
                       x, proj, yb, Kb, VWo, bo, out);
}

// Round 9
// 228.236 us; speedup vs baseline: 1.1183x; 1.1183x over previous
//
#include <hip/hip_runtime.h>
#include <math.h>

#define D_INN 256
#define D_HID 64
#define DTR 16
#define D_MEMM 128
#define BB 2
#define LL 2048
#define NROWS (BB*LL)   // 4096
#define NPROJ 736
#define NTOT 864        // 736 proj cols + 128 Q cols
#define SEG 16
#define SEGLEN (LL/SEG) // 128

typedef __attribute__((ext_vector_type(8))) short short8v;
typedef __attribute__((ext_vector_type(4))) float float4v;

static __device__ __forceinline__ unsigned short f2bf(float f) {
    unsigned int u = __float_as_uint(f);
    u += 0x7fff + ((u >> 16) & 1);   // RNE
    return (unsigned short)(u >> 16);
}

// ---------------- Kernel 1: proj = x @ [W_xproj | W_Q] (+b_Q), bf16 MFMA ----------------
__global__ __launch_bounds__(256) void k_gemm(const float* __restrict__ x,
        const float* __restrict__ Wx, const float* __restrict__ Wq,
        const float* __restrict__ bq, float* __restrict__ proj) {
    __shared__ unsigned short As[64][40];
    __shared__ unsigned short Bs[64][40];
    const int t = threadIdx.x;
    const int lane = t & 63, w = t >> 6;
    const int wr = w >> 1, wc = w & 1;
    const int row0 = blockIdx.y * 64, col0 = blockIdx.x * 64;

    float4v acc[2][2];
    #pragma unroll
    for (int i = 0; i < 2; i++)
        #pragma unroll
        for (int j = 0; j < 2; j++) acc[i][j] = (float4v)0.f;

    const int ar = t >> 2, akq = (t & 3) * 8;
    const int bk = t >> 3, bcq = (t & 7) * 8;

    for (int k0 = 0; k0 < D_INN; k0 += 32) {
        float4 a0 = *(const float4*)&x[(size_t)(row0 + ar) * D_INN + k0 + akq];
        float4 a1 = *(const float4*)&x[(size_t)(row0 + ar) * D_INN + k0 + akq + 4];
        float4 b0 = {}, b1 = {};
        int col = col0 + bcq;
        if (col + 8 <= NPROJ) {
            b0 = *(const float4*)&Wx[(size_t)(k0 + bk) * NPROJ + col];
            b1 = *(const float4*)&Wx[(size_t)(k0 + bk) * NPROJ + col + 4];
        } else if (col < NTOT) {
            b0 = *(const float4*)&Wq[(size_t)(k0 + bk) * D_MEMM + (col - NPROJ)];
            b1 = *(const float4*)&Wq[(size_t)(k0 + bk) * D_MEMM + (col - NPROJ) + 4];
        }
        __syncthreads();
        {
            unsigned short av[8] = { f2bf(a0.x), f2bf(a0.y), f2bf(a0.z), f2bf(a0.w),
                                     f2bf(a1.x), f2bf(a1.y), f2bf(a1.z), f2bf(a1.w) };
            *(short8v*)&As[ar][akq] = *(short8v*)av;
            Bs[bcq + 0][bk] = f2bf(b0.x); Bs[bcq + 1][bk] = f2bf(b0.y);
            Bs[bcq + 2][bk] = f2bf(b0.z); Bs[bcq + 3][bk] = f2bf(b0.w);
            Bs[bcq + 4][bk] = f2bf(b1.x); Bs[bcq + 5][bk] = f2bf(b1.y);
            Bs[bcq + 6][bk] = f2bf(b1.z); Bs[bcq + 7][bk] = f2bf(b1.w);
        }
        __syncthreads();
        short8v af[2], bf[2];
        const int fr = lane & 15, fk = (lane >> 4) * 8;
        af[0] = *(short8v*)&As[wr * 32 + fr][fk];
        af[1] = *(short8v*)&As[wr * 32 + 16 + fr][fk];
        bf[0] = *(short8v*)&Bs[wc * 32 + fr][fk];
        bf[1] = *(short8v*)&Bs[wc * 32 + 16 + fr][fk];
        #pragma unroll
        for (int i = 0; i < 2; i++)
            #pragma unroll
            for (int j = 0; j < 2; j++)
                acc[i][j] = __builtin_amdgcn_mfma_f32_16x16x32_bf16(af[i], bf[j], acc[i][j], 0, 0, 0);
    }
    #pragma unroll
    for (int i = 0; i < 2; i++)
        #pragma unroll
        for (int j = 0; j < 2; j++)
            #pragma unroll
            for (int e = 0; e < 4; e++) {
                int rr = row0 + wr * 32 + i * 16 + (lane >> 4) * 4 + e;
                int cc = col0 + wc * 32 + j * 16 + (lane & 15);
                if (cc < NTOT) {
                    float v = acc[i][j][e];
                    if (cc >= NPROJ) v += bq[cc - NPROJ];
                    proj[(size_t)rr * NTOT + cc] = v;
                }
            }
}

// ---------------- Kernel 2: delta / delta_l, 16 rows per block ----------------
__global__ __launch_bounds__(256) void k_delta(const float* __restrict__ proj,
        const float* __restrict__ Wdt, const float* __restrict__ bdt,
        const float* __restrict__ Wdtl, const float* __restrict__ bdtl,
        float* __restrict__ delta, float* __restrict__ deltal) {
    __shared__ float sdt[16][17], sdtl[16][17];
    const int t = threadIdx.x;
    const int r0 = blockIdx.x * 16;
    {
        int r = t >> 4, c = t & 15;
        sdt[r][c]  = proj[(size_t)(r0 + r) * NTOT + 704 + c];
        sdtl[r][c] = proj[(size_t)(r0 + r) * NTOT + 720 + c];
    }
    __syncthreads();
    float w1[DTR], w2[DTR];
    #pragma unroll
    for (int r = 0; r < DTR; r++) {
        w1[r] = Wdt[r * D_INN + t];
        w2[r] = Wdtl[r * D_INN + t];
    }
    const float b1 = bdt[t], b2 = bdtl[t];
    #pragma unroll
    for (int row = 0; row < 16; ++row) {
        float a1 = b1, a2 = b2;
        #pragma unroll
        for (int r = 0; r < DTR; r++) {
            a1 += sdt[row][r] * w1[r];
            a2 += sdtl[row][r] * w2[r];
        }
        delta[(size_t)(r0 + row) * D_INN + t]  = (a1 > 20.f) ? a1 : log1pf(expf(a1));
        deltal[(size_t)(r0 + row) * D_INN + t] = (a2 > 20.f) ? a2 : log1pf(expf(a2));
    }
}

// ---------------- Kernel 3a: pass 1 — no LDS, global-direct, register broadcast ----
__global__ __launch_bounds__(256) void k_scan1(const float* __restrict__ x,
        const float* __restrict__ proj, const float* __restrict__ A,
        const float* __restrict__ delta, const float* __restrict__ deltal,
        float* __restrict__ Qbuf, float* __restrict__ SDbuf,
        float* __restrict__ cumd, float* __restrict__ mem) {
    const int t = threadIdx.x;
    const int w = t >> 6, n = t & 63;
    const int b = blockIdx.y;
    const int scan = blockIdx.z >> 4, seg = blockIdx.z & 15;
    const int d = blockIdx.x * 4 + w;
    const size_t rowbase = (size_t)b * LL + (size_t)seg * SEGLEN;
    const float* dsel = (scan == 0 ? delta : deltal);
    const int cB = (scan == 0) ? 0 : 64;
    const float Aln = A[d * D_HID + n] * 1.44269504f;
    const int lr = n & 7;

    float s = 0.f, sd = 0.f;
    for (int c = 0; c < SEGLEN / 8; ++c) {
        const size_t l0 = rowbase + c * 8;
        float dvl = dsel[(l0 + lr) * D_INN + d];
        float pl  = dvl * x[(l0 + lr) * D_INN + d];
        float Bv[8];
        #pragma unroll
        for (int li = 0; li < 8; ++li) Bv[li] = proj[(l0 + li) * NTOT + cB + n];
        #pragma unroll
        for (int li = 0; li < 8; ++li) {
            float dv = __shfl(dvl, li);
            float p  = __shfl(pl, li);
            s = fmaf(exp2f(dv * Aln), s, p * Bv[li]);
            sd += dv;
            if (scan == 1 && li == 0 && (c & 1) == 0) {
                float v = s;
                #pragma unroll
                for (int off = 32; off >= 1; off >>= 1) v += __shfl_xor(v, off);
                if (n == 0) {
                    int k = seg * 8 + (c >> 1);
                    mem[((size_t)b * 128 + k) * D_INN + d] = v;
                    cumd[(((size_t)b * SEG + seg) * 8 + (c >> 1)) * D_INN + d] = sd;
                }
            }
        }
    }
    Qbuf[((((size_t)scan * 2 + b) * SEG + seg) * D_INN + d) * 64 + n] = s;
    if (n == 0) SDbuf[(((size_t)scan * 2 + b) * SEG + seg) * D_INN + d] = sd;
}

// ---------------- Kernel 3b: pass 2 — scan 0 only, global-direct, barrier-free ----
__global__ __launch_bounds__(256) void k_scan2(const float* __restrict__ x,
        const float* __restrict__ proj, const float* __restrict__ A,
        const float* __restrict__ Dp, const float* __restrict__ delta,
        const float* __restrict__ Qbuf, const float* __restrict__ SDbuf,
        float* __restrict__ y) {
    __shared__ float rbuf[4][8][65];
    const int t = threadIdx.x;
    const int w = t >> 6, n = t & 63;
    const int b = blockIdx.y, seg = blockIdx.z;
    const int d = blockIdx.x * 4 + w;
    const size_t rowbase = (size_t)b * LL + (size_t)seg * SEGLEN;
    const float Aln = A[d * D_HID + n] * 1.44269504f;
    const float Dpv = Dp[d];
    const int lr = n & 7;
    const int rli = n >> 3, g = n & 7;

    // s_in prefix over earlier segments (scan 0)
    float s = 0.f;
    for (int k = 0; k < seg; ++k) {
        float sdk = SDbuf[(((size_t)b * SEG + k) * D_INN + d)];
        float Qk = Qbuf[(((size_t)b * SEG + k) * D_INN + d) * 64 + n];
        s = fmaf(exp2f(sdk * Aln), s, Qk);
    }

    for (int c = 0; c < SEGLEN / 8; ++c) {
        const size_t l0 = rowbase + c * 8;
        float dvl = delta[(l0 + lr) * D_INN + d];
        float uvl = x[(l0 + lr) * D_INN + d];
        float pl = dvl * uvl;
        float Bv[8], Cv[8];
        #pragma unroll
        for (int li = 0; li < 8; ++li) {
            Bv[li] = proj[(l0 + li) * NTOT + n];
            Cv[li] = proj[(l0 + li) * NTOT + 128 + n];
        }
        #pragma unroll
        for (int li = 0; li < 8; ++li) {
            float dv = __shfl(dvl, li);
            float p  = __shfl(pl, li);
            s = fmaf(exp2f(dv * Aln), s, p * Bv[li]);
            rbuf[w][li][n] = s * Cv[li];
        }
        // same-wave reduce over n (no barrier: writes+reads within one wave)
        float acc = 0.f;
        #pragma unroll
        for (int j = 0; j < 8; ++j) acc += rbuf[w][rli][g * 8 + j];
        acc += __shfl_xor(acc, 1);
        acc += __shfl_xor(acc, 2);
        acc += __shfl_xor(acc, 4);
        float uv = __shfl(uvl, rli);   // all lanes active (shfl must NOT be in the guard)
        if (g == 0) {
            y[(l0 + rli) * D_INN + d] = acc + uv * Dpv;
        }
    }
}

// ---------------- Kernel 3c-1: segment-boundary states for scan=1 ----------------
__global__ __launch_bounds__(256) void k_sin(const float* __restrict__ A,
        const float* __restrict__ Qbuf, const float* __restrict__ SDbuf,
        float* __restrict__ Sin) {
    const int t = threadIdx.x, w = t >> 6, n = t & 63;
    const int b = blockIdx.y;
    const int d = blockIdx.x * 4 + w;
    const float Aln = A[d * D_HID + n] * 1.44269504f;
    float s = 0.f;
    #pragma unroll
    for (int seg = 0; seg < SEG; ++seg) {
        if (seg > 0) Sin[(((size_t)b * SEG + seg) * D_INN + d) * 64 + n] = s;
        float sdk = SDbuf[((size_t)(2 + b) * SEG + seg) * D_INN + d];
        float Qk = Qbuf[(((size_t)(2 + b) * SEG + seg) * D_INN + d) * 64 + n];
        s = fmaf(exp2f(sdk * Aln), s, Qk);
    }
}

// ---------------- Kernel 3c-2: parallel mem correction ----------------
__global__ __launch_bounds__(256) void k_fix(const float* __restrict__ A,
        const float* __restrict__ Sin, const float* __restrict__ cumd,
        float* __restrict__ mem) {
    const int t = threadIdx.x, w = t >> 6, n = t & 63;
    const int k = 8 + blockIdx.y;
    const int b = blockIdx.z;
    const int d = blockIdx.x * 4 + w;
    const int seg = k >> 3;
    const float Aln = A[d * D_HID + n] * 1.44269504f;
    float cum = cumd[((size_t)b * 128 + k) * D_INN + d];
    float sv = Sin[(((size_t)b * SEG + seg) * D_INN + d) * 64 + n];
    float v = exp2f(cum * Aln) * sv;
    #pragma unroll
    for (int off = 32; off >= 1; off >>= 1) v += __shfl_xor(v, off);
    if (n == 0) mem[((size_t)b * 128 + k) * D_INN + d] += v;
}

// ---------------- Kernel 4: fused K, V, VWo per memory row ----------------
__global__ __launch_bounds__(128) void k_kvwo(const float* __restrict__ mem,
        const float* __restrict__ Wk, const float* __restrict__ bk,
        const float* __restrict__ Wv, const float* __restrict__ bv,
        const float* __restrict__ Wo,
        float* __restrict__ K, float* __restrict__ VWo) {
    __shared__ float mrow[256];
    __shared__ float vrow[128];
    const int k = blockIdx.x, b = blockIdx.y;
    const int t = threadIdx.x;
    const float* mr = mem + ((size_t)b * 128 + k) * D_INN;
    mrow[t] = mr[t];
    mrow[t + 128] = mr[t + 128];
    __syncthreads();
    float aK = bk[t], aV = bv[t];
    for (int dd = 0; dd < D_INN; dd++) {
        float m = mrow[dd];
        aK += m * Wk[dd * D_MEMM + t];
        aV += m * Wv[dd * D_MEMM + t];
    }
    K[((size_t)b * 128 + k) * D_MEMM + t] = aK;
    vrow[t] = aV;
    __syncthreads();
    float a0 = 0.f, a1 = 0.f;
    for (int m = 0; m < 128; ++m) {
        float vm = vrow[m];
        a0 += vm * Wo[(size_t)m * D_INN + t];
        a1 += vm * Wo[(size_t)m * D_INN + t + 128];
    }
    VWo[((size_t)b * 128 + k) * D_INN + t] = a0;
    VWo[((size_t)b * 128 + k) * D_INN + t + 128] = a1;
}

// ---------------- Kernel 5: attention + epilogue, 16 rows per block ----------------
__global__ __launch_bounds__(256) void k_attn(const float* __restrict__ x,
        const float* __restrict__ proj, const float* __restrict__ y,
        const float* __restrict__ K, const float* __restrict__ VWo,
        const float* __restrict__ bo, float* __restrict__ out) {
    __shared__ float qs[16][132];
    __shared__ float ws[16][132];
    __shared__ float denom[16];
    const int t = threadIdx.x;
    const int b = blockIdx.y;
    const int r0 = blockIdx.x * 16;
    const size_t rowbase = (size_t)b * LL + r0;
    {
        int r = t >> 4, c8 = (t & 15) * 8;
        const float* src = &proj[(rowbase + r) * NTOT + NPROJ + c8];
        *(float4*)&qs[r][c8] = *(const float4*)src;
        *(float4*)&qs[r][c8 + 4] = *(const float4*)(src + 4);
    }
    __syncthreads();
    {
        const int k = t & 127, rg = (t >> 7) * 8;
        const float* Kr = K + ((size_t)b * 128 + k) * D_MEMM;
        float acc[8] = {};
        #pragma unroll 8
        for (int m = 0; m < 128; m += 4) {
            float4 kv = *(const float4*)&Kr[m];
            #pragma unroll
            for (int r = 0; r < 8; ++r) {
                float4 qv = *(const float4*)&qs[rg + r][m];
                acc[r] += qv.x * kv.x + qv.y * kv.y + qv.z * kv.z + qv.w * kv.w;
            }
        }
        #pragma unroll
        for (int r = 0; r < 8; ++r) ws[rg + r][k] = acc[r] * 0.125f;
    }
    __syncthreads();
    {
        const int r = t >> 4, j = t & 15;
        float4 v0 = *(float4*)&ws[r][j * 8];
        float4 v1 = *(float4*)&ws[r][j * 8 + 4];
        float mx = fmaxf(fmaxf(fmaxf(v0.x, v0.y), fmaxf(v0.z, v0.w)),
                         fmaxf(fmaxf(v1.x, v1.y), fmaxf(v1.z, v1.w)));
        #pragma unroll
        for (int o = 1; o < 16; o <<= 1) mx = fmaxf(mx, __shfl_xor(mx, o));
        v0.x = expf(v0.x - mx); v0.y = expf(v0.y - mx);
        v0.z = expf(v0.z - mx); v0.w = expf(v0.w - mx);
        v1.x = expf(v1.x - mx); v1.y = expf(v1.y - mx);
        v1.z = expf(v1.z - mx); v1.w = expf(v1.w - mx);
        float sum = v0.x + v0.y + v0.z + v0.w + v1.x + v1.y + v1.z + v1.w;
        #pragma unroll
        for (int o = 1; o < 16; o <<= 1) sum += __shfl_xor(sum, o);
        *(float4*)&ws[r][j * 8] = v0;
        *(float4*)&ws[r][j * 8 + 4] = v1;
        if (j == 0) denom[r] = sum;
    }
    __syncthreads();
    {
        const int w = t >> 6, lane = t & 63;
        const int c0 = lane * 4;
        const float* vb = VWo + (size_t)b * 128 * D_INN + c0;
        float acc[4][4] = {};
        #pragma unroll 8
        for (int k = 0; k < 128; k += 4) {
            float4 wv[4];
            #pragma unroll
            for (int r = 0; r < 4; ++r) wv[r] = *(float4*)&ws[w * 4 + r][k];
            #pragma unroll
            for (int kk = 0; kk < 4; ++kk) {
                float4 vw = *(const float4*)&vb[(size_t)(k + kk) * D_INN];
                #pragma unroll
                for (int r = 0; r < 4; ++r) {
                    float wk = (kk == 0 ? wv[r].x : kk == 1 ? wv[r].y : kk == 2 ? wv[r].z : wv[r].w);
                    acc[r][0] += wk * vw.x; acc[r][1] += wk * vw.y;
                    acc[r][2] += wk * vw.z; acc[r][3] += wk * vw.w;
                }
            }
        }
        float4 bov = *(const float4*)&bo[c0];
        #pragma unroll
        for (int r = 0; r < 4; ++r) {
            size_t rr = rowbase + w * 4 + r;
            float dn = 1.f / denom[w * 4 + r];
            float4 yv = *(const float4*)&y[rr * D_INN + c0];
            float4 xv = *(const float4*)&x[rr * D_INN + c0];
            float4 Ev = *(const float4*)&proj[rr * NTOT + 192 + c0];
            float4 Fv = *(const float4*)&proj[rr * NTOT + 448 + c0];
            float4 o;
            o.x = yv.x + (acc[r][0] * dn + bov.x) * Ev.x + xv.x * Fv.x;
            o.y = yv.y + (acc[r][1] * dn + bov.y) * Ev.y + xv.y * Fv.y;
            o.z = yv.z + (acc[r][2] * dn + bov.z) * Ev.z + xv.z * Fv.z;
            o.w = yv.w + (acc[r][3] * dn + bov.w) * Ev.w + xv.w * Fv.w;
            *(float4*)&out[rr * D_INN + c0] = o;
        }
    }
}

extern "C" void kernel_launch(void* const* d_in, const int* in_sizes, int n_in,
                              void* d_out, int out_size, void* d_ws, size_t ws_size,
                              hipStream_t stream) {
    const float* x    = (const float*)d_in[0];
    const float* Wx   = (const float*)d_in[1];
    const float* Wdt  = (const float*)d_in[2];
    const float* bdt  = (const float*)d_in[3];
    const float* Wdtl = (const float*)d_in[4];
    const float* bdtl = (const float*)d_in[5];
    const float* A    = (const float*)d_in[6];
    const float* Dp   = (const float*)d_in[7];
    const float* Wq   = (const float*)d_in[8];
    const float* bq   = (const float*)d_in[9];
    const float* Wk   = (const float*)d_in[10];
    const float* bk   = (const float*)d_in[11];
    const float* Wv   = (const float*)d_in[12];
    const float* bv   = (const float*)d_in[13];
    const float* Wo   = (const float*)d_in[14];
    const float* bo   = (const float*)d_in[15];
    float* out = (float*)d_out;
    float* ws = (float*)d_ws;

    float* proj   = ws;                                    // 4096*864
    float* delta  = proj + (size_t)NROWS * NTOT;           // 4096*256
    float* deltal = delta + (size_t)NROWS * D_INN;         // 4096*256
    float* yb     = deltal + (size_t)NROWS * D_INN;        // 4096*256
    float* mem    = yb + (size_t)NROWS * D_INN;            // 2*128*256
    float* Kb     = mem + (size_t)BB * 128 * D_INN;        // 2*128*128
    float* Qbuf   = Kb + (size_t)BB * 128 * D_MEMM;        // 4*16*256*64
    float* SDbuf  = Qbuf + (size_t)4 * SEG * D_INN * 64;   // 4*16*256
    float* cumd   = SDbuf + (size_t)4 * SEG * D_INN;       // 2*16*8*256
    float* Sin    = cumd + (size_t)BB * SEG * 8 * D_INN;   // 2*16*256*64
    float* VWo    = Sin + (size_t)BB * SEG * D_INN * 64;   // 2*128*256

    hipLaunchKernelGGL(k_gemm, dim3(14, 64), dim3(256), 0, stream, x, Wx, Wq, bq, proj);
    hipLaunchKernelGGL(k_delta, dim3(NROWS / 16), dim3(256), 0, stream,
                       proj, Wdt, bdt, Wdtl, bdtl, delta, deltal);
    hipLaunchKernelGGL(k_scan1, dim3(64, 2, 32), dim3(256), 0, stream,
                       x, proj, A, delta, deltal, Qbuf, SDbuf, cumd, mem);
    hipLaunchKernelGGL(k_scan2, dim3(64, 2, 16), dim3(256), 0, stream,
                       x, proj, A, Dp, delta, Qbuf, SDbuf, yb);
    hipLaunchKernelGGL(k_sin, dim3(64, 2), dim3(256), 0, stream,
                       A, Qbuf, SDbuf, Sin);
    hipLaunchKernelGGL(k_fix, dim3(64, 120, 2), dim3(256), 0, stream,
                       A, Sin, cumd, mem);
    hipLaunchKernelGGL(k_kvwo, dim3(128, 2), dim3(128), 0, stream,
                       mem, Wk, bk, Wv, bv, Wo, Kb, VWo);
    hipLaunchKernelGGL(k_attn, dim3(128, 2), dim3(256), 0, stream,
                       x, proj, yb, Kb, VWo, bo, out);
}

// Round 10
// 222.652 us; speedup vs baseline: 1.1464x; 1.0251x over previous
//
#include <hip/hip_runtime.h>
#include <math.h>

#define D_INN 256
#define D_HID 64
#define DTR 16
#define D_MEMM 128
#define BB 2
#define LL 2048
#define NROWS (BB*LL)   // 4096
#define NPROJ 736
#define NTOT 864        // 736 proj cols + 128 Q cols
#define SEG 16
#define SEGLEN (LL/SEG) // 128

typedef __attribute__((ext_vector_type(8))) short short8v;
typedef __attribute__((ext_vector_type(4))) float float4v;

static __device__ __forceinline__ unsigned short f2bf(float f) {
    unsigned int u = __float_as_uint(f);
    u += 0x7fff + ((u >> 16) & 1);   // RNE
    return (unsigned short)(u >> 16);
}

static __device__ __forceinline__ float rdlane(float v, int l) {
    return __uint_as_float(__builtin_amdgcn_readlane(__float_as_uint(v), l));
}

// ---------------- Kernel 1: proj = x @ [W_xproj | W_Q] (+b_Q), bf16 MFMA ----------------
__global__ __launch_bounds__(256) void k_gemm(const float* __restrict__ x,
        const float* __restrict__ Wx, const float* __restrict__ Wq,
        const float* __restrict__ bq, float* __restrict__ proj) {
    __shared__ unsigned short As[64][40];
    __shared__ unsigned short Bs[64][40];
    const int t = threadIdx.x;
    const int lane = t & 63, w = t >> 6;
    const int wr = w >> 1, wc = w & 1;
    const int row0 = blockIdx.y * 64, col0 = blockIdx.x * 64;

    float4v acc[2][2];
    #pragma unroll
    for (int i = 0; i < 2; i++)
        #pragma unroll
        for (int j = 0; j < 2; j++) acc[i][j] = (float4v)0.f;

    const int ar = t >> 2, akq = (t & 3) * 8;
    const int bk = t >> 3, bcq = (t & 7) * 8;

    for (int k0 = 0; k0 < D_INN; k0 += 32) {
        float4 a0 = *(const float4*)&x[(size_t)(row0 + ar) * D_INN + k0 + akq];
        float4 a1 = *(const float4*)&x[(size_t)(row0 + ar) * D_INN + k0 + akq + 4];
        float4 b0 = {}, b1 = {};
        int col = col0 + bcq;
        if (col + 8 <= NPROJ) {
            b0 = *(const float4*)&Wx[(size_t)(k0 + bk) * NPROJ + col];
            b1 = *(const float4*)&Wx[(size_t)(k0 + bk) * NPROJ + col + 4];
        } else if (col < NTOT) {
            b0 = *(const float4*)&Wq[(size_t)(k0 + bk) * D_MEMM + (col - NPROJ)];
            b1 = *(const float4*)&Wq[(size_t)(k0 + bk) * D_MEMM + (col - NPROJ) + 4];
        }
        __syncthreads();
        {
            unsigned short av[8] = { f2bf(a0.x), f2bf(a0.y), f2bf(a0.z), f2bf(a0.w),
                                     f2bf(a1.x), f2bf(a1.y), f2bf(a1.z), f2bf(a1.w) };
            *(short8v*)&As[ar][akq] = *(short8v*)av;
            Bs[bcq + 0][bk] = f2bf(b0.x); Bs[bcq + 1][bk] = f2bf(b0.y);
            Bs[bcq + 2][bk] = f2bf(b0.z); Bs[bcq + 3][bk] = f2bf(b0.w);
            Bs[bcq + 4][bk] = f2bf(b1.x); Bs[bcq + 5][bk] = f2bf(b1.y);
            Bs[bcq + 6][bk] = f2bf(b1.z); Bs[bcq + 7][bk] = f2bf(b1.w);
        }
        __syncthreads();
        short8v af[2], bf[2];
        const int fr = lane & 15, fk = (lane >> 4) * 8;
        af[0] = *(short8v*)&As[wr * 32 + fr][fk];
        af[1] = *(short8v*)&As[wr * 32 + 16 + fr][fk];
        bf[0] = *(short8v*)&Bs[wc * 32 + fr][fk];
        bf[1] = *(short8v*)&Bs[wc * 32 + 16 + fr][fk];
        #pragma unroll
        for (int i = 0; i < 2; i++)
            #pragma unroll
            for (int j = 0; j < 2; j++)
                acc[i][j] = __builtin_amdgcn_mfma_f32_16x16x32_bf16(af[i], bf[j], acc[i][j], 0, 0, 0);
    }
    #pragma unroll
    for (int i = 0; i < 2; i++)
        #pragma unroll
        for (int j = 0; j < 2; j++)
            #pragma unroll
            for (int e = 0; e < 4; e++) {
                int rr = row0 + wr * 32 + i * 16 + (lane >> 4) * 4 + e;
                int cc = col0 + wc * 32 + j * 16 + (lane & 15);
                if (cc < NTOT) {
                    float v = acc[i][j][e];
                    if (cc >= NPROJ) v += bq[cc - NPROJ];
                    proj[(size_t)rr * NTOT + cc] = v;
                }
            }
}

// ---------------- Kernel 1b: xT[b][d][l] = x[b][l][d] (64x64 LDS transpose) ----------------
__global__ __launch_bounds__(256) void k_xt(const float* __restrict__ x,
        float* __restrict__ xT) {
    __shared__ float tile[64][65];
    const int t = threadIdx.x;
    const int lt = blockIdx.x * 64, dt = blockIdx.y * 64, b = blockIdx.z;
    const int c = t & 63, rg = (t >> 6) * 16;
    #pragma unroll
    for (int j = 0; j < 16; ++j)
        tile[rg + j][c] = x[((size_t)b * LL + lt + rg + j) * D_INN + dt + c];
    __syncthreads();
    #pragma unroll
    for (int j = 0; j < 16; ++j)
        xT[((size_t)b * D_INN + dt + rg + j) * LL + lt + c] = tile[c][rg + j];
}

// ---------------- Kernel 2: delta / delta_l, transposed outputs [d][l] ----------------
__global__ __launch_bounds__(256) void k_delta(const float* __restrict__ proj,
        const float* __restrict__ Wdt, const float* __restrict__ bdt,
        const float* __restrict__ Wdtl, const float* __restrict__ bdtl,
        float* __restrict__ deltaT, float* __restrict__ deltalT) {
    __shared__ float sdt[16][17], sdtl[16][17];
    const int t = threadIdx.x;
    const int r0 = blockIdx.x * 16;
    const int b = r0 >> 11, l0 = r0 & (LL - 1);
    {
        int r = t >> 4, c = t & 15;
        sdt[r][c]  = proj[(size_t)(r0 + r) * NTOT + 704 + c];
        sdtl[r][c] = proj[(size_t)(r0 + r) * NTOT + 720 + c];
    }
    __syncthreads();
    float w1[DTR], w2[DTR];
    #pragma unroll
    for (int r = 0; r < DTR; r++) {
        w1[r] = Wdt[r * D_INN + t];
        w2[r] = Wdtl[r * D_INN + t];
    }
    const float b1 = bdt[t], b2 = bdtl[t];
    float o1[16], o2[16];
    #pragma unroll
    for (int row = 0; row < 16; ++row) {
        float a1 = b1, a2 = b2;
        #pragma unroll
        for (int r = 0; r < DTR; r++) {
            a1 += sdt[row][r] * w1[r];
            a2 += sdtl[row][r] * w2[r];
        }
        o1[row] = (a1 > 20.f) ? a1 : log1pf(expf(a1));
        o2[row] = (a2 > 20.f) ? a2 : log1pf(expf(a2));
    }
    float* p1 = &deltaT[((size_t)b * D_INN + t) * LL + l0];
    float* p2 = &deltalT[((size_t)b * D_INN + t) * LL + l0];
    #pragma unroll
    for (int j = 0; j < 16; j += 4) {
        *(float4*)&p1[j] = make_float4(o1[j], o1[j+1], o1[j+2], o1[j+3]);
        *(float4*)&p2[j] = make_float4(o2[j], o2[j+1], o2[j+2], o2[j+3]);
    }
}

// ---------------- Kernel 3a: pass 1 — transposed δ/x, readlane broadcasts ----------------
__global__ __launch_bounds__(256) void k_scan1(const float* __restrict__ xT,
        const float* __restrict__ proj, const float* __restrict__ A,
        const float* __restrict__ deltaT, const float* __restrict__ deltalT,
        float* __restrict__ Qbuf, float* __restrict__ SDbuf,
        float* __restrict__ cumd, float* __restrict__ mem) {
    const int t = threadIdx.x;
    const int w = t >> 6, n = t & 63;
    const int b = blockIdx.y;
    const int scan = blockIdx.z >> 4, seg = blockIdx.z & 15;
    const int d = blockIdx.x * 4 + w;
    const size_t rowbase = (size_t)b * LL + (size_t)seg * SEGLEN;
    const float* dT = (scan == 0 ? deltaT : deltalT) + ((size_t)b * D_INN + d) * LL + seg * SEGLEN;
    const float* uT = xT + ((size_t)b * D_INN + d) * LL + seg * SEGLEN;
    const int cB = (scan == 0) ? 0 : 64;
    const float Aln = A[d * D_HID + n] * 1.44269504f;
    const int lr = n & 7;

    float s = 0.f, sd = 0.f;
    for (int c = 0; c < SEGLEN / 8; ++c) {
        const size_t l0 = rowbase + c * 8;
        float dvl = dT[c * 8 + lr];
        float pl  = dvl * uT[c * 8 + lr];
        float Bv[8];
        #pragma unroll
        for (int li = 0; li < 8; ++li) Bv[li] = proj[(l0 + li) * NTOT + cB + n];
        #pragma unroll
        for (int li = 0; li < 8; ++li) {
            float dv = rdlane(dvl, li);
            float p  = rdlane(pl, li);
            s = fmaf(exp2f(dv * Aln), s, p * Bv[li]);
            sd += dv;
            if (scan == 1 && li == 0 && (c & 1) == 0) {
                float v = s;
                #pragma unroll
                for (int off = 32; off >= 1; off >>= 1) v += __shfl_xor(v, off);
                if (n == 0) {
                    int k = seg * 8 + (c >> 1);
                    mem[((size_t)b * 128 + k) * D_INN + d] = v;
                    cumd[(((size_t)b * SEG + seg) * 8 + (c >> 1)) * D_INN + d] = sd;
                }
            }
        }
    }
    Qbuf[((((size_t)scan * 2 + b) * SEG + seg) * D_INN + d) * 64 + n] = s;
    if (n == 0) SDbuf[(((size_t)scan * 2 + b) * SEG + seg) * D_INN + d] = sd;
}

// ---------------- Kernel 3b: pass 2 — scan 0 only, transposed δ/x, readlane ----------------
__global__ __launch_bounds__(256) void k_scan2(const float* __restrict__ xT,
        const float* __restrict__ proj, const float* __restrict__ A,
        const float* __restrict__ Dp, const float* __restrict__ deltaT,
        const float* __restrict__ Qbuf, const float* __restrict__ SDbuf,
        float* __restrict__ y) {
    __shared__ float rbuf[4][8][65];
    const int t = threadIdx.x;
    const int w = t >> 6, n = t & 63;
    const int b = blockIdx.y, seg = blockIdx.z;
    const int d = blockIdx.x * 4 + w;
    const size_t rowbase = (size_t)b * LL + (size_t)seg * SEGLEN;
    const float* dT = deltaT + ((size_t)b * D_INN + d) * LL + seg * SEGLEN;
    const float* uT = xT + ((size_t)b * D_INN + d) * LL + seg * SEGLEN;
    const float Aln = A[d * D_HID + n] * 1.44269504f;
    const float Dpv = Dp[d];
    const int lr = n & 7;
    const int rli = n >> 3, g = n & 7;

    // s_in prefix over earlier segments (scan 0)
    float s = 0.f;
    for (int k = 0; k < seg; ++k) {
        float sdk = SDbuf[(((size_t)b * SEG + k) * D_INN + d)];
        float Qk = Qbuf[(((size_t)b * SEG + k) * D_INN + d) * 64 + n];
        s = fmaf(exp2f(sdk * Aln), s, Qk);
    }

    for (int c = 0; c < SEGLEN / 8; ++c) {
        const size_t l0 = rowbase + c * 8;
        float dvl = dT[c * 8 + lr];
        float uvl = uT[c * 8 + lr];
        float pl = dvl * uvl;
        float Bv[8], Cv[8];
        #pragma unroll
        for (int li = 0; li < 8; ++li) {
            Bv[li] = proj[(l0 + li) * NTOT + n];
            Cv[li] = proj[(l0 + li) * NTOT + 128 + n];
        }
        #pragma unroll
        for (int li = 0; li < 8; ++li) {
            float dv = rdlane(dvl, li);
            float p  = rdlane(pl, li);
            s = fmaf(exp2f(dv * Aln), s, p * Bv[li]);
            rbuf[w][li][n] = s * Cv[li];
        }
        // same-wave reduce over n (no barrier: writes+reads within one wave)
        float acc = 0.f;
        #pragma unroll
        for (int j = 0; j < 8; ++j) acc += rbuf[w][rli][g * 8 + j];
        acc += __shfl_xor(acc, 1);
        acc += __shfl_xor(acc, 2);
        acc += __shfl_xor(acc, 4);
        float uv = __shfl(uvl, rli);   // lane-varying index: must stay outside the guard
        if (g == 0) {
            y[(l0 + rli) * D_INN + d] = acc + uv * Dpv;
        }
    }
}

// ---------------- Kernel 3c-1: segment-boundary states for scan=1 ----------------
__global__ __launch_bounds__(256) void k_sin(const float* __restrict__ A,
        const float* __restrict__ Qbuf, const float* __restrict__ SDbuf,
        float* __restrict__ Sin) {
    const int t = threadIdx.x, w = t >> 6, n = t & 63;
    const int b = blockIdx.y;
    const int d = blockIdx.x * 4 + w;
    const float Aln = A[d * D_HID + n] * 1.44269504f;
    float s = 0.f;
    #pragma unroll
    for (int seg = 0; seg < SEG; ++seg) {
        if (seg > 0) Sin[(((size_t)b * SEG + seg) * D_INN + d) * 64 + n] = s;
        float sdk = SDbuf[((size_t)(2 + b) * SEG + seg) * D_INN + d];
        float Qk = Qbuf[(((size_t)(2 + b) * SEG + seg) * D_INN + d) * 64 + n];
        s = fmaf(exp2f(sdk * Aln), s, Qk);
    }
}

// ---------------- Kernel 3c-2: parallel mem correction ----------------
__global__ __launch_bounds__(256) void k_fix(const float* __restrict__ A,
        const float* __restrict__ Sin, const float* __restrict__ cumd,
        float* __restrict__ mem) {
    const int t = threadIdx.x, w = t >> 6, n = t & 63;
    const int k = 8 + blockIdx.y;
    const int b = blockIdx.z;
    const int d = blockIdx.x * 4 + w;
    const int seg = k >> 3;
    const float Aln = A[d * D_HID + n] * 1.44269504f;
    float cum = cumd[((size_t)b * 128 + k) * D_INN + d];
    float sv = Sin[(((size_t)b * SEG + seg) * D_INN + d) * 64 + n];
    float v = exp2f(cum * Aln) * sv;
    #pragma unroll
    for (int off = 32; off >= 1; off >>= 1) v += __shfl_xor(v, off);
    if (n == 0) mem[((size_t)b * 128 + k) * D_INN + d] += v;
}

// ---------------- Kernel 4: fused K, V, VWo per memory row ----------------
__global__ __launch_bounds__(128) void k_kvwo(const float* __restrict__ mem,
        const float* __restrict__ Wk, const float* __restrict__ bk,
        const float* __restrict__ Wv, const float* __restrict__ bv,
        const float* __restrict__ Wo,
        float* __restrict__ K, float* __restrict__ VWo) {
    __shared__ float mrow[256];
    __shared__ float vrow[128];
    const int k = blockIdx.x, b = blockIdx.y;
    const int t = threadIdx.x;
    const float* mr = mem + ((size_t)b * 128 + k) * D_INN;
    mrow[t] = mr[t];
    mrow[t + 128] = mr[t + 128];
    __syncthreads();
    float aK = bk[t], aV = bv[t];
    for (int dd = 0; dd < D_INN; dd++) {
        float m = mrow[dd];
        aK += m * Wk[dd * D_MEMM + t];
        aV += m * Wv[dd * D_MEMM + t];
    }
    K[((size_t)b * 128 + k) * D_MEMM + t] = aK;
    vrow[t] = aV;
    __syncthreads();
    float a0 = 0.f, a1 = 0.f;
    for (int m = 0; m < 128; ++m) {
        float vm = vrow[m];
        a0 += vm * Wo[(size_t)m * D_INN + t];
        a1 += vm * Wo[(size_t)m * D_INN + t + 128];
    }
    VWo[((size_t)b * 128 + k) * D_INN + t] = a0;
    VWo[((size_t)b * 128 + k) * D_INN + t + 128] = a1;
}

// ---------------- Kernel 5: attention + epilogue, 16 rows per block ----------------
__global__ __launch_bounds__(256) void k_attn(const float* __restrict__ x,
        const float* __restrict__ proj, const float* __restrict__ y,
        const float* __restrict__ K, const float* __restrict__ VWo,
        const float* __restrict__ bo, float* __restrict__ out) {
    __shared__ float qs[16][132];
    __shared__ float ws[16][132];
    __shared__ float denom[16];
    const int t = threadIdx.x;
    const int b = blockIdx.y;
    const int r0 = blockIdx.x * 16;
    const size_t rowbase = (size_t)b * LL + r0;
    {
        int r = t >> 4, c8 = (t & 15) * 8;
        const float* src = &proj[(rowbase + r) * NTOT + NPROJ + c8];
        *(float4*)&qs[r][c8] = *(const float4*)src;
        *(float4*)&qs[r][c8 + 4] = *(const float4*)(src + 4);
    }
    __syncthreads();
    {
        const int k = t & 127, rg = (t >> 7) * 8;
        const float* Kr = K + ((size_t)b * 128 + k) * D_MEMM;
        float acc[8] = {};
        #pragma unroll 8
        for (int m = 0; m < 128; m += 4) {
            float4 kv = *(const float4*)&Kr[m];
            #pragma unroll
            for (int r = 0; r < 8; ++r) {
                float4 qv = *(const float4*)&qs[rg + r][m];
                acc[r] += qv.x * kv.x + qv.y * kv.y + qv.z * kv.z + qv.w * kv.w;
            }
        }
        #pragma unroll
        for (int r = 0; r < 8; ++r) ws[rg + r][k] = acc[r] * 0.125f;
    }
    __syncthreads();
    {
        const int r = t >> 4, j = t & 15;
        float4 v0 = *(float4*)&ws[r][j * 8];
        float4 v1 = *(float4*)&ws[r][j * 8 + 4];
        float mx = fmaxf(fmaxf(fmaxf(v0.x, v0.y), fmaxf(v0.z, v0.w)),
                         fmaxf(fmaxf(v1.x, v1.y), fmaxf(v1.z, v1.w)));
        #pragma unroll
        for (int o = 1; o < 16; o <<= 1) mx = fmaxf(mx, __shfl_xor(mx, o));
        v0.x = expf(v0.x - mx); v0.y = expf(v0.y - mx);
        v0.z = expf(v0.z - mx); v0.w = expf(v0.w - mx);
        v1.x = expf(v1.x - mx); v1.y = expf(v1.y - mx);
        v1.z = expf(v1.z - mx); v1.w = expf(v1.w - mx);
        float sum = v0.x + v0.y + v0.z + v0.w + v1.x + v1.y + v1.z + v1.w;
        #pragma unroll
        for (int o = 1; o < 16; o <<= 1) sum += __shfl_xor(sum, o);
        *(float4*)&ws[r][j * 8] = v0;
        *(float4*)&ws[r][j * 8 + 4] = v1;
        if (j == 0) denom[r] = sum;
    }
    __syncthreads();
    {
        const int w = t >> 6, lane = t & 63;
        const int c0 = lane * 4;
        const float* vb = VWo + (size_t)b * 128 * D_INN + c0;
        float acc[4][4] = {};
        #pragma unroll 8
        for (int k = 0; k < 128; k += 4) {
            float4 wv[4];
            #pragma unroll
            for (int r = 0; r < 4; ++r) wv[r] = *(float4*)&ws[w * 4 + r][k];
            #pragma unroll
            for (int kk = 0; kk < 4; ++kk) {
                float4 vw = *(const float4*)&vb[(size_t)(k + kk) * D_INN];
                #pragma unroll
                for (int r = 0; r < 4; ++r) {
                    float wk = (kk == 0 ? wv[r].x : kk == 1 ? wv[r].y : kk == 2 ? wv[r].z : wv[r].w);
                    acc[r][0] += wk * vw.x; acc[r][1] += wk * vw.y;
                    acc[r][2] += wk * vw.z; acc[r][3] += wk * vw.w;
                }
            }
        }
        float4 bov = *(const float4*)&bo[c0];
        #pragma unroll
        for (int r = 0; r < 4; ++r) {
            size_t rr = rowbase + w * 4 + r;
            float dn = 1.f / denom[w * 4 + r];
            float4 yv = *(const float4*)&y[rr * D_INN + c0];
            float4 xv = *(const float4*)&x[rr * D_INN + c0];
            float4 Ev = *(const float4*)&proj[rr * NTOT + 192 + c0];
            float4 Fv = *(const float4*)&proj[rr * NTOT + 448 + c0];
            float4 o;
            o.x = yv.x + (acc[r][0] * dn + bov.x) * Ev.x + xv.x * Fv.x;
            o.y = yv.y + (acc[r][1] * dn + bov.y) * Ev.y + xv.y * Fv.y;
            o.z = yv.z + (acc[r][2] * dn + bov.z) * Ev.z + xv.z * Fv.z;
            o.w = yv.w + (acc[r][3] * dn + bov.w) * Ev.w + xv.w * Fv.w;
            *(float4*)&out[rr * D_INN + c0] = o;
        }
    }
}

extern "C" void kernel_launch(void* const* d_in, const int* in_sizes, int n_in,
                              void* d_out, int out_size, void* d_ws, size_t ws_size,
                              hipStream_t stream) {
    const float* x    = (const float*)d_in[0];
    const float* Wx   = (const float*)d_in[1];
    const float* Wdt  = (const float*)d_in[2];
    const float* bdt  = (const float*)d_in[3];
    const float* Wdtl = (const float*)d_in[4];
    const float* bdtl = (const float*)d_in[5];
    const float* A    = (const float*)d_in[6];
    const float* Dp   = (const float*)d_in[7];
    const float* Wq   = (const float*)d_in[8];
    const float* bq   = (const float*)d_in[9];
    const float* Wk   = (const float*)d_in[10];
    const float* bk   = (const float*)d_in[11];
    const float* Wv   = (const float*)d_in[12];
    const float* bv   = (const float*)d_in[13];
    const float* Wo   = (const float*)d_in[14];
    const float* bo   = (const float*)d_in[15];
    float* out = (float*)d_out;
    float* ws = (float*)d_ws;

    float* proj    = ws;                                    // 4096*864
    float* deltaT  = proj + (size_t)NROWS * NTOT;           // [b][d][l] 2*256*2048
    float* deltalT = deltaT + (size_t)NROWS * D_INN;        // [b][d][l]
    float* yb      = deltalT + (size_t)NROWS * D_INN;       // 4096*256
    float* mem     = yb + (size_t)NROWS * D_INN;            // 2*128*256
    float* Kb      = mem + (size_t)BB * 128 * D_INN;        // 2*128*128
    float* Qbuf    = Kb + (size_t)BB * 128 * D_MEMM;        // 4*16*256*64
    float* SDbuf   = Qbuf + (size_t)4 * SEG * D_INN * 64;   // 4*16*256
    float* cumd    = SDbuf + (size_t)4 * SEG * D_INN;       // 2*16*8*256
    float* Sin     = cumd + (size_t)BB * SEG * 8 * D_INN;   // 2*16*256*64
    float* VWo     = Sin + (size_t)BB * SEG * D_INN * 64;   // 2*128*256
    float* xT      = VWo + (size_t)BB * 128 * D_INN;        // [b][d][l] 2*256*2048

    hipLaunchKernelGGL(k_gemm, dim3(14, 64), dim3(256), 0, stream, x, Wx, Wq, bq, proj);
    hipLaunchKernelGGL(k_xt, dim3(32, 4, 2), dim3(256), 0, stream, x, xT);
    hipLaunchKernelGGL(k_delta, dim3(NROWS / 16), dim3(256), 0, stream,
                       proj, Wdt, bdt, Wdtl, bdtl, deltaT, deltalT);
    hipLaunchKernelGGL(k_scan1, dim3(64, 2, 32), dim3(256), 0, stream,
                       xT, proj, A, deltaT, deltalT, Qbuf, SDbuf, cumd, mem);
    hipLaunchKernelGGL(k_scan2, dim3(64, 2, 16), dim3(256), 0, stream,
                       xT, proj, A, Dp, deltaT, Qbuf, SDbuf, yb);
    hipLaunchKernelGGL(k_sin, dim3(64, 2), dim3(256), 0, stream,
                       A, Qbuf, SDbuf, Sin);
    hipLaunchKernelGGL(k_fix, dim3(64, 120, 2), dim3(256), 0, stream,
                       A, Sin, cumd, mem);
    hipLaunchKernelGGL(k_kvwo, dim3(128, 2), dim3(128), 0, stream,
                       mem, Wk, bk, Wv, bv, Wo, Kb, VWo);
    hipLaunchKernelGGL(k_attn, dim3(128, 2), dim3(256), 0, stream,
                       x, proj, yb, Kb, VWo, bo, out);
}